// Round 4
// baseline (185.723 us; speedup 1.0000x reference)
//
#include <hip/hip_runtime.h>
#include <math.h>

// Chamfer distance, B=4, N=M=8192, fp32.
// Output layout (flat float32): dist1[B*N], dist2[B*M], idx1[B*N] (as float),
// idx2[B*M] (as float).
//
// R13: R12 verbatim except the inner distance computation is packed 2-wide
// (float2 / VOP3P v_pk_add/mul/fma_f32). R10 (ILP) and R12 (TLP) were both
// null -> the ~66% issue efficiency is structural; the remaining lever is
// instruction COUNT. Pairing the 8 ref points into 4 float2 vectors turns
// 48 scalar distance instrs per query-group into 24 packed ones. pk ops are
// per-component IEEE-identical to their scalar forms (and (-a)*(-a) == a*a
// bitwise), so results are bitwise identical; min-tree, strict-< earliest-
// group update, packed u64 atomicMin, and chamfer_final are untouched.
//
// Tie semantics (unchanged): equal dist bits -> atomicMin picks the smallest
// global group id (groups partition index space in order); within the group
// the descending scan in chamfer_final ends at the smallest matching p ==
// np.argmin first-occurrence.
//
// Semantics: d = fmaf(dx,dx,fmaf(dy,dy,dz*dz)) per component (rounding delta
// ~ulp(d) vs reference, flip-safe: ~2300x below typical top-2 gaps -> absmax
// 0 measured R5-R12).

#define QPT 4         // queries per thread
#define BLK 256       // threads per block
#define QPB (QPT*BLK) // queries per block = 1024

typedef float v2f __attribute__((ext_vector_type(2)));

__global__ __launch_bounds__(256, 8) void chamfer_main(
    const float* __restrict__ xyz1, const float* __restrict__ xyz2,
    unsigned long long* __restrict__ pp,
    int N, int M, int B, int S, int C)
{
    const int dir = blockIdx.z;          // 0: xyz1->xyz2, 1: xyz2->xyz1
    const float* q = dir ? xyz2 : xyz1;  // query cloud
    const float* r = dir ? xyz1 : xyz2;  // reference cloud
    const int Nq = dir ? M : N;
    const int Nr = dir ? N : M;
    const int b     = blockIdx.y / S;
    const int split = blockIdx.y % S;
    const int base  = split * C;         // this block's ref-index range [base, base+C)

    extern __shared__ float s[];         // C*3 floats

    // cooperative vectorized tile load (C%8==0 -> byte count divisible by 16)
    {
        const float4* gv = (const float4*)(r + ((size_t)b * Nr + base) * 3);
        float4* sv = (float4*)s;
        const int elems4 = C * 3 / 4;
        for (int t = threadIdx.x; t < elems4; t += BLK) sv[t] = gv[t];
    }
    __syncthreads();

    // load 4 query points (stride-BLK within the block's query window)
    float qx[QPT], qy[QPT], qz[QPT];
    int qi[QPT];
    bool qv[QPT];
#pragma unroll
    for (int k = 0; k < QPT; ++k) {
        qi[k] = blockIdx.x * QPB + k * BLK + threadIdx.x;
        qv[k] = qi[k] < Nq;
        const float* qp = q + ((size_t)b * Nq + (qv[k] ? qi[k] : 0)) * 3;
        qx[k] = qp[0]; qy[k] = qp[1]; qz[k] = qp[2];
    }

    // per-query running min + winning 8-group id (block-local)
    float bd[QPT];
    int   gi[QPT];
#pragma unroll
    for (int k = 0; k < QPT; ++k) { bd[k] = INFINITY; gi[k] = 0; }

    const float4* sv = (const float4*)s;
    const int iters = C / 8;
    for (int j8 = 0; j8 < iters; ++j8) {
        // 24 floats = 8 ref points; all lanes same address -> LDS broadcast
        float4 f0 = sv[6 * j8 + 0];
        float4 f1 = sv[6 * j8 + 1];
        float4 f2 = sv[6 * j8 + 2];
        float4 f3 = sv[6 * j8 + 3];
        float4 f4 = sv[6 * j8 + 4];
        float4 f5 = sv[6 * j8 + 5];
        // pack the 8 points as 4 float2 per coordinate (register halves; free)
        v2f px2[4] = { {f0.x, f0.w}, {f1.z, f2.y}, {f3.x, f3.w}, {f4.z, f5.y} };
        v2f py2[4] = { {f0.y, f1.x}, {f1.w, f2.z}, {f3.y, f4.x}, {f4.w, f5.z} };
        v2f pz2[4] = { {f0.z, f1.y}, {f2.x, f2.w}, {f3.z, f4.y}, {f5.x, f5.w} };
#pragma unroll
        for (int k = 0; k < QPT; ++k) {
            v2f d2[4];
#pragma unroll
            for (int m = 0; m < 4; ++m) {
                v2f dx = qx[k] - px2[m];   // scalar splats; v_pk_add (neg)
                v2f dy = qy[k] - py2[m];
                v2f dz = qz[k] - pz2[m];
                v2f t  = dz * dz;                               // v_pk_mul
                t      = __builtin_elementwise_fma(dy, dy, t);  // v_pk_fma
                d2[m]  = __builtin_elementwise_fma(dx, dx, t);  // v_pk_fma
            }
            // min-of-8 as min3 x3 + min (exact; value independent of tree shape)
            float t0 = fminf(fminf(d2[0].x, d2[0].y), d2[1].x);
            float t1 = fminf(fminf(d2[1].y, d2[2].x), d2[2].y);
            float t2 = fminf(fminf(d2[3].x, d2[3].y), t0);
            float m  = fminf(t1, t2);
            // strict < keeps the EARLIEST group attaining the min value
            if (m < bd[k]) { bd[k] = m; gi[k] = j8; }
        }
    }

    // fold (dist_bits, global group id) into the per-query slot.
    // d >= 0 -> float bits order-monotonic as unsigned; low 32 bits carry the
    // group id so equal-dist ties resolve to the smallest group == smallest
    // global index's group.
    const size_t obase = (size_t)(dir * B + b) * Nq;
    const int gbase = split * (C / 8);   // global group base for this block
#pragma unroll
    for (int k = 0; k < QPT; ++k) {
        if (!qv[k]) continue;
        unsigned long long packed =
            ((unsigned long long)__float_as_uint(bd[k]) << 32)
            | (unsigned)(gbase + gi[k]);
        atomicMin(&pp[obase + qi[k]], packed);
    }
}

__global__ __launch_bounds__(256) void chamfer_final(
    const float* __restrict__ xyz1, const float* __restrict__ xyz2,
    const unsigned long long* __restrict__ pp,
    float* __restrict__ out, int N, int M, int B)
{
    const int gid = blockIdx.x * blockDim.x + threadIdx.x;
    const int perDir0 = B * N;
    int dir, rem;
    if (gid < perDir0) { dir = 0; rem = gid; }
    else if (gid < perDir0 + B * M) { dir = 1; rem = gid - perDir0; }
    else return;
    const int Nq = dir ? M : N;
    const int Nr = dir ? N : M;
    const float* q = dir ? xyz2 : xyz1;
    const float* r = dir ? xyz1 : xyz2;

    // pp is [2][B][Nq] flat; rem = b*Nq + i
    unsigned long long v = pp[(size_t)(dir * B) * Nq + rem];
    const unsigned bits = (unsigned)(v >> 32);
    const int grp = (int)(v & 0xffffffffu);

    const int b  = rem / Nq;
    const int qi = rem - b * Nq;
    const float* qp = q + ((size_t)b * Nq + qi) * 3;
    const float qx = qp[0], qy = qp[1], qz = qp[2];

    // gather the winning 8-point group from global (L2-resident), recompute
    // with the SAME fmaf expression on the SAME input bits -> bitwise match.
    const float4* rv = (const float4*)(r + ((size_t)b * Nr + (size_t)grp * 8) * 3);
    float4 f0 = rv[0], f1 = rv[1], f2 = rv[2], f3 = rv[3], f4 = rv[4], f5 = rv[5];
    float px[8] = { f0.x, f0.w, f1.z, f2.y, f3.x, f3.w, f4.z, f5.y };
    float py[8] = { f0.y, f1.x, f1.w, f2.z, f3.y, f4.x, f4.w, f5.z };
    float pz[8] = { f0.z, f1.y, f2.x, f2.w, f3.z, f4.y, f5.x, f5.w };
    int best = 0;
#pragma unroll
    for (int p = 7; p >= 0; --p) {       // descending: ends at SMALLEST match
        float dx = qx - px[p];
        float dy = qy - py[p];
        float dz = qz - pz[p];
        float d = fmaf(dx, dx, fmaf(dy, dy, dz * dz));
        if (__float_as_uint(d) == bits) best = p;  // match guaranteed (same bits)
    }
    const int idx = grp * 8 + best;

    float* dist_out = out + (dir ? (size_t)B * N : 0);
    float* idx_out  = out + (size_t)B * N + (size_t)B * M + (dir ? (size_t)B * N : 0);
    dist_out[rem] = __uint_as_float(bits);
    idx_out[rem]  = (float)idx;
}

extern "C" void kernel_launch(void* const* d_in, const int* in_sizes, int n_in,
                              void* d_out, int out_size, void* d_ws, size_t ws_size,
                              hipStream_t stream) {
    const float* xyz1 = (const float*)d_in[0];
    const float* xyz2 = (const float*)d_in[1];
    float* out = (float*)d_out;
    const int B = 4;
    const int N = in_sizes[0] / (B * 3);
    const int M = in_sizes[1] / (B * 3);
    const int NQ = (N > M ? N : M);
    const int NR = (N > M ? N : M);

    int S = 32;
    while (NR % (S * 8)) S >>= 1;  // need C = NR/S divisible by 8
    const int C = NR / S;

    unsigned long long* pp = (unsigned long long*)d_ws;  // [2][B][NQ] packed slots
    const int nslots = 2 * B * NQ;

    // init pp to ~0ULL via byte-pattern memset (0xFF) — graph-capturable
    // memset node, replaces the init kernel (one fewer dispatch + gap).
    hipMemsetAsync(pp, 0xFF, (size_t)nslots * 8, stream);

    dim3 grid((NQ + QPB - 1) / QPB, B * S, 2);
    size_t lds = (size_t)C * 3 * sizeof(float);
    chamfer_main<<<grid, dim3(BLK, 1, 1), lds, stream>>>(
        xyz1, xyz2, pp, N, M, B, S, C);

    chamfer_final<<<dim3((nslots + 255) / 256, 1, 1), dim3(256, 1, 1), 0, stream>>>(
        xyz1, xyz2, pp, out, N, M, B);
}

// Round 5
// 133.710 us; speedup vs baseline: 1.3890x; 1.3890x over previous
//
#include <hip/hip_runtime.h>
#include <math.h>

// Chamfer distance, B=4, N=M=8192, fp32.
// Output layout (flat float32): dist1[B*N], dist2[B*M], idx1[B*N] (as float),
// idx2[B*M] (as float).
//
// R14: e-form inner loop (3 fma/pair) with a provable exactness guard.
// R12's 72us fits a 3cy/VALU-slot issue model at 98% -> only lever left is
// instruction COUNT. LDS tile becomes float4 (x,y,z,rr=|r|^2) per point;
// per query a=-2q (exact); e = fma(ax,rx,fma(ay,ry,fma(az,rz,rr))) orders
// identically to true distance in real arithmetic. Rounding error of the
// e-chain is bounded by ~1.9e-6*(qq+2*Rb), Rb=(|q|+sqrt(d1+0.01))^2 bounding
// any contender's |r|^2. Guard: if top-2 group-min e-gap <= eps=4e-6*(qq+2Rb)
// (2x margin), rebuild the contender set exactly: cheap e-pass collects all
// groups with m_e <= e1+eps into a bitmask (superset of any group that could
// win under R12's d-form), then an exact d-form scan of masked groups with
// R12's ascending strict-< semantics picks the winner. Unflagged queries'
// winning group provably equals R12's. Winner group always gets an exact
// d-form recompute; the atomic packs (d_bits<<32|global_group) exactly as
// R12; chamfer_final unchanged -> outputs bitwise identical to R12.
//
// R13 lesson: no ext-vector math types / runtime-indexed vector arrays
// (scratch demotion, 2x regression). Named float4s + constant-index scalars.
//
// Tie semantics (unchanged): equal d bits -> atomicMin picks the smallest
// global group id; d-ties between groups imply e-gap ~0 -> flagged -> exact
// path reproduces R12's earliest-group strict-<. chamfer_final's descending
// scan ends at the smallest matching p == np.argmin first-occurrence.

#define QPT 4         // queries per thread
#define BLK 256       // threads per block
#define QPB (QPT*BLK) // queries per block = 1024

// load 8 ref float4s (one group) from LDS into named registers
#define LOADF8(J) do {                                                        \
    f0 = sv4[8*(J)+0]; f1 = sv4[8*(J)+1]; f2 = sv4[8*(J)+2];                  \
    f3 = sv4[8*(J)+3]; f4 = sv4[8*(J)+4]; f5 = sv4[8*(J)+5];                  \
    f6 = sv4[8*(J)+6]; f7 = sv4[8*(J)+7];                                     \
} while (0)

// e-form group min: m = min_p fma(AX,x, fma(AY,y, fma(AZ,z, rr)))
#define EMIN8(AX, AY, AZ, MOUT) do {                                          \
    float d0 = fmaf(AX, f0.x, fmaf(AY, f0.y, fmaf(AZ, f0.z, f0.w)));          \
    float d1 = fmaf(AX, f1.x, fmaf(AY, f1.y, fmaf(AZ, f1.z, f1.w)));          \
    float d2 = fmaf(AX, f2.x, fmaf(AY, f2.y, fmaf(AZ, f2.z, f2.w)));          \
    float d3 = fmaf(AX, f3.x, fmaf(AY, f3.y, fmaf(AZ, f3.z, f3.w)));          \
    float d4 = fmaf(AX, f4.x, fmaf(AY, f4.y, fmaf(AZ, f4.z, f4.w)));          \
    float d5 = fmaf(AX, f5.x, fmaf(AY, f5.y, fmaf(AZ, f5.z, f5.w)));          \
    float d6 = fmaf(AX, f6.x, fmaf(AY, f6.y, fmaf(AZ, f6.z, f6.w)));          \
    float d7 = fmaf(AX, f7.x, fmaf(AY, f7.y, fmaf(AZ, f7.z, f7.w)));          \
    float t0 = fminf(fminf(d0, d1), d2);                                      \
    float t1 = fminf(fminf(d3, d4), d5);                                      \
    float t2 = fminf(fminf(d6, d7), t0);                                      \
    MOUT = fminf(t1, t2);                                                     \
} while (0)

// exact d-form group min (R12 expression, bitwise-compatible with final)
#define DMIN8(QX, QY, QZ, MOUT) do {                                          \
    float dx, dy, dz;                                                         \
    dx = QX - f0.x; dy = QY - f0.y; dz = QZ - f0.z;                           \
    float d0 = fmaf(dx, dx, fmaf(dy, dy, dz * dz));                           \
    dx = QX - f1.x; dy = QY - f1.y; dz = QZ - f1.z;                           \
    float d1 = fmaf(dx, dx, fmaf(dy, dy, dz * dz));                           \
    dx = QX - f2.x; dy = QY - f2.y; dz = QZ - f2.z;                           \
    float d2 = fmaf(dx, dx, fmaf(dy, dy, dz * dz));                           \
    dx = QX - f3.x; dy = QY - f3.y; dz = QZ - f3.z;                           \
    float d3 = fmaf(dx, dx, fmaf(dy, dy, dz * dz));                           \
    dx = QX - f4.x; dy = QY - f4.y; dz = QZ - f4.z;                           \
    float d4 = fmaf(dx, dx, fmaf(dy, dy, dz * dz));                           \
    dx = QX - f5.x; dy = QY - f5.y; dz = QZ - f5.z;                           \
    float d5 = fmaf(dx, dx, fmaf(dy, dy, dz * dz));                           \
    dx = QX - f6.x; dy = QY - f6.y; dz = QZ - f6.z;                           \
    float d6 = fmaf(dx, dx, fmaf(dy, dy, dz * dz));                           \
    dx = QX - f7.x; dy = QY - f7.y; dz = QZ - f7.z;                           \
    float d7 = fmaf(dx, dx, fmaf(dy, dy, dz * dz));                           \
    float t0 = fminf(fminf(d0, d1), d2);                                      \
    float t1 = fminf(fminf(d3, d4), d5);                                      \
    float t2 = fminf(fminf(d6, d7), t0);                                      \
    MOUT = fminf(t1, t2);                                                     \
} while (0)

__global__ __launch_bounds__(256, 4) void chamfer_main(
    const float* __restrict__ xyz1, const float* __restrict__ xyz2,
    unsigned long long* __restrict__ pp,
    int N, int M, int B, int S, int C)
{
    const int dir = blockIdx.z;          // 0: xyz1->xyz2, 1: xyz2->xyz1
    const float* q = dir ? xyz2 : xyz1;  // query cloud
    const float* r = dir ? xyz1 : xyz2;  // reference cloud
    const int Nq = dir ? M : N;
    const int Nr = dir ? N : M;
    const int b     = blockIdx.y / S;
    const int split = blockIdx.y % S;
    const int base  = split * C;         // this block's ref-index range [base, base+C)

    extern __shared__ float s[];         // C float4s: (x,y,z,rr)
    float4* sv4 = (float4*)s;

    // stage tile: repack packed-xyz -> float4(x,y,z,rr). rr deterministic
    // per point; only feeds e-comparisons (never output values).
    {
        const float* g3 = r + ((size_t)b * Nr + base) * 3;
        for (int t = threadIdx.x; t < C; t += BLK) {
            float gx = g3[3 * t + 0];
            float gy = g3[3 * t + 1];
            float gz = g3[3 * t + 2];
            float rr = fmaf(gz, gz, fmaf(gy, gy, gx * gx));
            float4 f; f.x = gx; f.y = gy; f.z = gz; f.w = rr;
            sv4[t] = f;
        }
    }
    __syncthreads();

    // load 4 query points; keep a = -2*q (exact; q recoverable as -0.5*a)
    float ax[QPT], ay[QPT], az[QPT];
    int qi[QPT];
    bool qvv[QPT];
#pragma unroll
    for (int k = 0; k < QPT; ++k) {
        qi[k] = blockIdx.x * QPB + k * BLK + threadIdx.x;
        qvv[k] = qi[k] < Nq;
        const float* qp = q + ((size_t)b * Nq + (qvv[k] ? qi[k] : 0)) * 3;
        ax[k] = -2.0f * qp[0]; ay[k] = -2.0f * qp[1]; az[k] = -2.0f * qp[2];
    }

    // per-query: top-2 group-min e values + winning group id
    float e1[QPT], e2[QPT];
    int   g1[QPT];
#pragma unroll
    for (int k = 0; k < QPT; ++k) { e1[k] = INFINITY; e2[k] = INFINITY; g1[k] = 0; }

    const int iters = C / 8;             // <= 64 (mask is u64)
    for (int j8 = 0; j8 < iters; ++j8) {
        float4 f0, f1, f2, f3, f4, f5, f6, f7;
        LOADF8(j8);                      // all lanes same addr -> LDS broadcast
#pragma unroll
        for (int k = 0; k < QPT; ++k) {
            float m;
            EMIN8(ax[k], ay[k], az[k], m);
            float h = fmaxf(e1[k], m);
            e2[k] = fminf(e2[k], h);     // runner-up group-min
            if (m < e1[k]) g1[k] = j8;   // strict <: earliest group on e-ties
            e1[k] = fminf(e1[k], m);
        }
    }

    const size_t obase = (size_t)(dir * B + b) * Nq;
    const int gbase = split * (C / 8);   // global group base for this block
#pragma unroll
    for (int k = 0; k < QPT; ++k) {
        if (!qvv[k]) continue;
        // exact query coords (bitwise original: a = -2q exact, -0.5*a = q)
        const float qx = -0.5f * ax[k], qy = -0.5f * ay[k], qz = -0.5f * az[k];
        int gi = g1[k];
        {
            // eps bound: contenders (d <= d1+slack) have rr <= Rb =
            // (|q|+sqrt(d1e+0.01))^2; e-chain error per point <= ~5 ulps of
            // (qq+2rr) plus d-form ulps -> total < 1.9e-6*(qq+2Rb); use 4e-6.
            float qq  = fmaf(qx, qx, fmaf(qy, qy, qz * qz));
            float d1e = qq + e1[k];
            float rt  = sqrtf(qq) + sqrtf(fmaxf(d1e, 0.0f) + 0.01f);
            float eps = 4e-6f * fmaf(2.0f, rt * rt, qq);
            if (e2[k] - e1[k] <= eps) {
                // ambiguous under error bound: collect ALL groups whose
                // e-min could beat the winner (superset of d-contenders)...
                const float lim = e1[k] + eps;
                unsigned long long mask = 0ull;
                for (int j8 = 0; j8 < iters; ++j8) {
                    float4 f0, f1, f2, f3, f4, f5, f6, f7;
                    LOADF8(j8);
                    float m;
                    EMIN8(ax[k], ay[k], az[k], m);   // bitwise same as pass 1
                    if (m <= lim) mask |= 1ull << j8;
                }
                // ...then resolve exactly with R12's d-form + semantics.
                float bdx = INFINITY; int gs = 0;
                for (int j8 = 0; j8 < iters; ++j8) {
                    if (!((mask >> j8) & 1)) continue;
                    float4 f0, f1, f2, f3, f4, f5, f6, f7;
                    LOADF8(j8);
                    float md;
                    DMIN8(qx, qy, qz, md);
                    if (md < bdx) { bdx = md; gs = j8; }  // earliest group
                }
                gi = gs;
            }
        }
        // exact d-form min of the winning group -> packed atomic (R12 scheme)
        float m;
        {
            float4 f0, f1, f2, f3, f4, f5, f6, f7;
            LOADF8(gi);
            DMIN8(qx, qy, qz, m);
        }
        unsigned long long packed =
            ((unsigned long long)__float_as_uint(m) << 32)
            | (unsigned)(gbase + gi);
        atomicMin(&pp[obase + qi[k]], packed);
    }
}

__global__ __launch_bounds__(256) void chamfer_final(
    const float* __restrict__ xyz1, const float* __restrict__ xyz2,
    const unsigned long long* __restrict__ pp,
    float* __restrict__ out, int N, int M, int B)
{
    const int gid = blockIdx.x * blockDim.x + threadIdx.x;
    const int perDir0 = B * N;
    int dir, rem;
    if (gid < perDir0) { dir = 0; rem = gid; }
    else if (gid < perDir0 + B * M) { dir = 1; rem = gid - perDir0; }
    else return;
    const int Nq = dir ? M : N;
    const int Nr = dir ? N : M;
    const float* q = dir ? xyz2 : xyz1;
    const float* r = dir ? xyz1 : xyz2;

    // pp is [2][B][Nq] flat; rem = b*Nq + i
    unsigned long long v = pp[(size_t)(dir * B) * Nq + rem];
    const unsigned bits = (unsigned)(v >> 32);
    const int grp = (int)(v & 0xffffffffu);

    const int b  = rem / Nq;
    const int qi = rem - b * Nq;
    const float* qp = q + ((size_t)b * Nq + qi) * 3;
    const float qx = qp[0], qy = qp[1], qz = qp[2];

    // gather the winning 8-point group from global (L2-resident), recompute
    // with the SAME fmaf expression on the SAME input bits -> bitwise match.
    const float4* rv = (const float4*)(r + ((size_t)b * Nr + (size_t)grp * 8) * 3);
    float4 f0 = rv[0], f1 = rv[1], f2 = rv[2], f3 = rv[3], f4 = rv[4], f5 = rv[5];
    float px[8] = { f0.x, f0.w, f1.z, f2.y, f3.x, f3.w, f4.z, f5.y };
    float py[8] = { f0.y, f1.x, f1.w, f2.z, f3.y, f4.x, f4.w, f5.z };
    float pz[8] = { f0.z, f1.y, f2.x, f2.w, f3.z, f4.y, f5.x, f5.w };
    int best = 0;
#pragma unroll
    for (int p = 7; p >= 0; --p) {       // descending: ends at SMALLEST match
        float dx = qx - px[p];
        float dy = qy - py[p];
        float dz = qz - pz[p];
        float d = fmaf(dx, dx, fmaf(dy, dy, dz * dz));
        if (__float_as_uint(d) == bits) best = p;  // match guaranteed (same bits)
    }
    const int idx = grp * 8 + best;

    float* dist_out = out + (dir ? (size_t)B * N : 0);
    float* idx_out  = out + (size_t)B * N + (size_t)B * M + (dir ? (size_t)B * N : 0);
    dist_out[rem] = __uint_as_float(bits);
    idx_out[rem]  = (float)idx;
}

extern "C" void kernel_launch(void* const* d_in, const int* in_sizes, int n_in,
                              void* d_out, int out_size, void* d_ws, size_t ws_size,
                              hipStream_t stream) {
    const float* xyz1 = (const float*)d_in[0];
    const float* xyz2 = (const float*)d_in[1];
    float* out = (float*)d_out;
    const int B = 4;
    const int N = in_sizes[0] / (B * 3);
    const int M = in_sizes[1] / (B * 3);
    const int NQ = (N > M ? N : M);
    const int NR = (N > M ? N : M);

    int S = 32;
    while (NR % (S * 8)) S >>= 1;  // need C = NR/S divisible by 8
    const int C = NR / S;          // C/8 groups <= 64 (u64 mask)

    unsigned long long* pp = (unsigned long long*)d_ws;  // [2][B][NQ] packed slots
    const int nslots = 2 * B * NQ;

    // init pp to ~0ULL via byte-pattern memset (0xFF) — graph-capturable
    // memset node, replaces the init kernel (one fewer dispatch + gap).
    hipMemsetAsync(pp, 0xFF, (size_t)nslots * 8, stream);

    dim3 grid((NQ + QPB - 1) / QPB, B * S, 2);
    size_t lds = (size_t)C * 4 * sizeof(float);   // float4 per ref point
    chamfer_main<<<grid, dim3(BLK, 1, 1), lds, stream>>>(
        xyz1, xyz2, pp, N, M, B, S, C);

    chamfer_final<<<dim3((nslots + 255) / 256, 1, 1), dim3(256, 1, 1), 0, stream>>>(
        xyz1, xyz2, pp, out, N, M, B);
}

// Round 6
// 120.179 us; speedup vs baseline: 1.5454x; 1.1126x over previous
//
#include <hip/hip_runtime.h>
#include <math.h>

// Chamfer distance, B=4, N=M=8192, fp32.
// Output layout (flat float32): dist1[B*N], dist2[B*M], idx1[B*N] (as float),
// idx2[B*M] (as float).
//
// R15: R14's e-form loop (3 fma/pair + provable guard, absmax 0 verified)
// with the winner recompute moved OFF the divergent-LDS path. R14 regressed
// (72->87us) because LOADF8(gi) with per-lane gi at 128B stride hit one bank
// quad -> SQ_LDS_BANK_CONFLICT 0 -> 12.9M cycles (~21us). Now unflagged
// queries gather their winning group's 8 points from GLOBAL memory (L1/L2-
// resident, same 96B pattern chamfer_final uses; global gathers have no LDS
// bank conflicts) and compute the exact d-form min there. Flagged queries
// (rare) already produce exact d in their uniform-address LDS scan. Same
// (d_bits<<32|global_group) atomic, same final kernel -> outputs bitwise
// identical to R12/R14.
//
// Guard (unchanged from R14): e = fma(ax,rx,fma(ay,ry,fma(az,rz,rr))),
// a=-2q exact, rr=|r|^2. If top-2 group-min e-gap <= eps=4e-6*(qq+2Rb)
// (2x margin over the ~1.9e-6*(qq+2Rb) error bound, Rb=(|q|+sqrt(d1+.01))^2),
// rebuild contender set via e-pass bitmask, resolve exactly with R12's
// d-form ascending strict-< scan. Unflagged winner group provably == R12's.
//
// R13 lesson: named float4s + constant-index scalars only (no ext-vector
// math, no runtime-indexed arrays -> no scratch).
//
// Tie semantics: equal d bits -> atomicMin picks smallest global group;
// chamfer_final's descending scan ends at smallest matching p == np.argmin
// first-occurrence.

#define QPT 4         // queries per thread
#define BLK 256       // threads per block
#define QPB (QPT*BLK) // queries per block = 1024

// load 8 ref float4s (one group) from LDS into named registers
#define LOADF8(J) do {                                                        \
    f0 = sv4[8*(J)+0]; f1 = sv4[8*(J)+1]; f2 = sv4[8*(J)+2];                  \
    f3 = sv4[8*(J)+3]; f4 = sv4[8*(J)+4]; f5 = sv4[8*(J)+5];                  \
    f6 = sv4[8*(J)+6]; f7 = sv4[8*(J)+7];                                     \
} while (0)

// e-form group min: m = min_p fma(AX,x, fma(AY,y, fma(AZ,z, rr)))
#define EMIN8(AX, AY, AZ, MOUT) do {                                          \
    float d0 = fmaf(AX, f0.x, fmaf(AY, f0.y, fmaf(AZ, f0.z, f0.w)));          \
    float d1 = fmaf(AX, f1.x, fmaf(AY, f1.y, fmaf(AZ, f1.z, f1.w)));          \
    float d2 = fmaf(AX, f2.x, fmaf(AY, f2.y, fmaf(AZ, f2.z, f2.w)));          \
    float d3 = fmaf(AX, f3.x, fmaf(AY, f3.y, fmaf(AZ, f3.z, f3.w)));          \
    float d4 = fmaf(AX, f4.x, fmaf(AY, f4.y, fmaf(AZ, f4.z, f4.w)));          \
    float d5 = fmaf(AX, f5.x, fmaf(AY, f5.y, fmaf(AZ, f5.z, f5.w)));          \
    float d6 = fmaf(AX, f6.x, fmaf(AY, f6.y, fmaf(AZ, f6.z, f6.w)));          \
    float d7 = fmaf(AX, f7.x, fmaf(AY, f7.y, fmaf(AZ, f7.z, f7.w)));          \
    float t0 = fminf(fminf(d0, d1), d2);                                      \
    float t1 = fminf(fminf(d3, d4), d5);                                      \
    float t2 = fminf(fminf(d6, d7), t0);                                      \
    MOUT = fminf(t1, t2);                                                     \
} while (0)

// exact d-form group min on LDS float4s f0..f7 (R12 expression; min value is
// exact and tree-shape independent -> bitwise-compatible with chamfer_final)
#define DMIN8(QX, QY, QZ, MOUT) do {                                          \
    float dx, dy, dz;                                                         \
    dx = QX - f0.x; dy = QY - f0.y; dz = QZ - f0.z;                           \
    float d0 = fmaf(dx, dx, fmaf(dy, dy, dz * dz));                           \
    dx = QX - f1.x; dy = QY - f1.y; dz = QZ - f1.z;                           \
    float d1 = fmaf(dx, dx, fmaf(dy, dy, dz * dz));                           \
    dx = QX - f2.x; dy = QY - f2.y; dz = QZ - f2.z;                           \
    float d2 = fmaf(dx, dx, fmaf(dy, dy, dz * dz));                           \
    dx = QX - f3.x; dy = QY - f3.y; dz = QZ - f3.z;                           \
    float d3 = fmaf(dx, dx, fmaf(dy, dy, dz * dz));                           \
    dx = QX - f4.x; dy = QY - f4.y; dz = QZ - f4.z;                           \
    float d4 = fmaf(dx, dx, fmaf(dy, dy, dz * dz));                           \
    dx = QX - f5.x; dy = QY - f5.y; dz = QZ - f5.z;                           \
    float d5 = fmaf(dx, dx, fmaf(dy, dy, dz * dz));                           \
    dx = QX - f6.x; dy = QY - f6.y; dz = QZ - f6.z;                           \
    float d6 = fmaf(dx, dx, fmaf(dy, dy, dz * dz));                           \
    dx = QX - f7.x; dy = QY - f7.y; dz = QZ - f7.z;                           \
    float d7 = fmaf(dx, dx, fmaf(dy, dy, dz * dz));                           \
    float t0 = fminf(fminf(d0, d1), d2);                                      \
    float t1 = fminf(fminf(d3, d4), d5);                                      \
    float t2 = fminf(fminf(d6, d7), t0);                                      \
    MOUT = fminf(t1, t2);                                                     \
} while (0)

__global__ __launch_bounds__(256, 4) void chamfer_main(
    const float* __restrict__ xyz1, const float* __restrict__ xyz2,
    unsigned long long* __restrict__ pp,
    int N, int M, int B, int S, int C)
{
    const int dir = blockIdx.z;          // 0: xyz1->xyz2, 1: xyz2->xyz1
    const float* q = dir ? xyz2 : xyz1;  // query cloud
    const float* r = dir ? xyz1 : xyz2;  // reference cloud
    const int Nq = dir ? M : N;
    const int Nr = dir ? N : M;
    const int b     = blockIdx.y / S;
    const int split = blockIdx.y % S;
    const int base  = split * C;         // this block's ref-index range [base, base+C)

    extern __shared__ float s[];         // C float4s: (x,y,z,rr)
    float4* sv4 = (float4*)s;

    // stage tile: repack packed-xyz -> float4(x,y,z,rr). rr deterministic
    // per point; only feeds e-comparisons (never output values).
    {
        const float* g3 = r + ((size_t)b * Nr + base) * 3;
        for (int t = threadIdx.x; t < C; t += BLK) {
            float gx = g3[3 * t + 0];
            float gy = g3[3 * t + 1];
            float gz = g3[3 * t + 2];
            float rr = fmaf(gz, gz, fmaf(gy, gy, gx * gx));
            float4 f; f.x = gx; f.y = gy; f.z = gz; f.w = rr;
            sv4[t] = f;
        }
    }
    __syncthreads();

    // load 4 query points; keep a = -2*q (exact; q recoverable as -0.5*a)
    float ax[QPT], ay[QPT], az[QPT];
    int qi[QPT];
    bool qvv[QPT];
#pragma unroll
    for (int k = 0; k < QPT; ++k) {
        qi[k] = blockIdx.x * QPB + k * BLK + threadIdx.x;
        qvv[k] = qi[k] < Nq;
        const float* qp = q + ((size_t)b * Nq + (qvv[k] ? qi[k] : 0)) * 3;
        ax[k] = -2.0f * qp[0]; ay[k] = -2.0f * qp[1]; az[k] = -2.0f * qp[2];
    }

    // per-query: top-2 group-min e values + winning group id
    float e1[QPT], e2[QPT];
    int   g1[QPT];
#pragma unroll
    for (int k = 0; k < QPT; ++k) { e1[k] = INFINITY; e2[k] = INFINITY; g1[k] = 0; }

    const int iters = C / 8;             // <= 64 (mask is u64)
    for (int j8 = 0; j8 < iters; ++j8) {
        float4 f0, f1, f2, f3, f4, f5, f6, f7;
        LOADF8(j8);                      // all lanes same addr -> LDS broadcast
#pragma unroll
        for (int k = 0; k < QPT; ++k) {
            float m;
            EMIN8(ax[k], ay[k], az[k], m);
            float h = fmaxf(e1[k], m);
            e2[k] = fminf(e2[k], h);     // runner-up group-min
            if (m < e1[k]) g1[k] = j8;   // strict <: earliest group on e-ties
            e1[k] = fminf(e1[k], m);
        }
    }

    const size_t obase = (size_t)(dir * B + b) * Nq;
    const int gbase = split * (C / 8);   // global group base for this block
#pragma unroll
    for (int k = 0; k < QPT; ++k) {
        if (!qvv[k]) continue;
        // exact query coords (bitwise original: a = -2q exact, -0.5*a = q)
        const float qx = -0.5f * ax[k], qy = -0.5f * ay[k], qz = -0.5f * az[k];
        int gi = g1[k];
        float dwin;
        bool resolved = false;
        {
            // eps bound: contenders (d <= d1+slack) have rr <= Rb =
            // (|q|+sqrt(d1e+0.01))^2; e-chain error per point <= ~5 ulps of
            // (qq+2rr) plus d-form ulps -> total < 1.9e-6*(qq+2Rb); use 4e-6.
            float qq  = fmaf(qx, qx, fmaf(qy, qy, qz * qz));
            float d1e = qq + e1[k];
            float rt  = sqrtf(qq) + sqrtf(fmaxf(d1e, 0.0f) + 0.01f);
            float eps = 4e-6f * fmaf(2.0f, rt * rt, qq);
            if (e2[k] - e1[k] <= eps) {
                // ambiguous under error bound: collect ALL groups whose
                // e-min could beat the winner (superset of d-contenders)...
                const float lim = e1[k] + eps;
                unsigned long long mask = 0ull;
                for (int j8 = 0; j8 < iters; ++j8) {
                    float4 f0, f1, f2, f3, f4, f5, f6, f7;
                    LOADF8(j8);          // uniform addr -> broadcast, no conflicts
                    float m;
                    EMIN8(ax[k], ay[k], az[k], m);   // bitwise same as pass 1
                    if (m <= lim) mask |= 1ull << j8;
                }
                // ...then resolve exactly with R12's d-form + semantics.
                float bdx = INFINITY; int gs = 0;
                for (int j8 = 0; j8 < iters; ++j8) {
                    if (!((mask >> j8) & 1)) continue;
                    float4 f0, f1, f2, f3, f4, f5, f6, f7;
                    LOADF8(j8);          // uniform addr -> broadcast
                    float md;
                    DMIN8(qx, qy, qz, md);
                    if (md < bdx) { bdx = md; gs = j8; }  // earliest group
                }
                gi = gs; dwin = bdx; resolved = true;
            }
        }
        if (!resolved) {
            // exact d-form min of winner group, gathered from GLOBAL memory
            // (L1/L2-resident; avoids R14's divergent-LDS bank conflicts).
            // Same input bits as the LDS copy -> identical d bits.
            const float4* rv =
                (const float4*)(r + ((size_t)b * Nr + base + (size_t)gi * 8) * 3);
            float4 h0 = rv[0], h1 = rv[1], h2 = rv[2],
                   h3 = rv[3], h4 = rv[4], h5 = rv[5];
            float px[8] = { h0.x, h0.w, h1.z, h2.y, h3.x, h3.w, h4.z, h5.y };
            float py[8] = { h0.y, h1.x, h1.w, h2.z, h3.y, h4.x, h4.w, h5.z };
            float pz[8] = { h0.z, h1.y, h2.x, h2.w, h3.z, h4.y, h5.x, h5.w };
            float d[8];
#pragma unroll
            for (int p = 0; p < 8; ++p) {
                float dx = qx - px[p];
                float dy = qy - py[p];
                float dz = qz - pz[p];
                d[p] = fmaf(dx, dx, fmaf(dy, dy, dz * dz));
            }
            float t0 = fminf(fminf(d[0], d[1]), d[2]);
            float t1 = fminf(fminf(d[3], d[4]), d[5]);
            float t2 = fminf(fminf(d[6], d[7]), t0);
            dwin = fminf(t1, t2);
        }
        unsigned long long packed =
            ((unsigned long long)__float_as_uint(dwin) << 32)
            | (unsigned)(gbase + gi);
        atomicMin(&pp[obase + qi[k]], packed);
    }
}

__global__ __launch_bounds__(256) void chamfer_final(
    const float* __restrict__ xyz1, const float* __restrict__ xyz2,
    const unsigned long long* __restrict__ pp,
    float* __restrict__ out, int N, int M, int B)
{
    const int gid = blockIdx.x * blockDim.x + threadIdx.x;
    const int perDir0 = B * N;
    int dir, rem;
    if (gid < perDir0) { dir = 0; rem = gid; }
    else if (gid < perDir0 + B * M) { dir = 1; rem = gid - perDir0; }
    else return;
    const int Nq = dir ? M : N;
    const int Nr = dir ? N : M;
    const float* q = dir ? xyz2 : xyz1;
    const float* r = dir ? xyz1 : xyz2;

    // pp is [2][B][Nq] flat; rem = b*Nq + i
    unsigned long long v = pp[(size_t)(dir * B) * Nq + rem];
    const unsigned bits = (unsigned)(v >> 32);
    const int grp = (int)(v & 0xffffffffu);

    const int b  = rem / Nq;
    const int qi = rem - b * Nq;
    const float* qp = q + ((size_t)b * Nq + qi) * 3;
    const float qx = qp[0], qy = qp[1], qz = qp[2];

    // gather the winning 8-point group from global (L2-resident), recompute
    // with the SAME fmaf expression on the SAME input bits -> bitwise match.
    const float4* rv = (const float4*)(r + ((size_t)b * Nr + (size_t)grp * 8) * 3);
    float4 f0 = rv[0], f1 = rv[1], f2 = rv[2], f3 = rv[3], f4 = rv[4], f5 = rv[5];
    float px[8] = { f0.x, f0.w, f1.z, f2.y, f3.x, f3.w, f4.z, f5.y };
    float py[8] = { f0.y, f1.x, f1.w, f2.z, f3.y, f4.x, f4.w, f5.z };
    float pz[8] = { f0.z, f1.y, f2.x, f2.w, f3.z, f4.y, f5.x, f5.w };
    int best = 0;
#pragma unroll
    for (int p = 7; p >= 0; --p) {       // descending: ends at SMALLEST match
        float dx = qx - px[p];
        float dy = qy - py[p];
        float dz = qz - pz[p];
        float d = fmaf(dx, dx, fmaf(dy, dy, dz * dz));
        if (__float_as_uint(d) == bits) best = p;  // match guaranteed (same bits)
    }
    const int idx = grp * 8 + best;

    float* dist_out = out + (dir ? (size_t)B * N : 0);
    float* idx_out  = out + (size_t)B * N + (size_t)B * M + (dir ? (size_t)B * N : 0);
    dist_out[rem] = __uint_as_float(bits);
    idx_out[rem]  = (float)idx;
}

extern "C" void kernel_launch(void* const* d_in, const int* in_sizes, int n_in,
                              void* d_out, int out_size, void* d_ws, size_t ws_size,
                              hipStream_t stream) {
    const float* xyz1 = (const float*)d_in[0];
    const float* xyz2 = (const float*)d_in[1];
    float* out = (float*)d_out;
    const int B = 4;
    const int N = in_sizes[0] / (B * 3);
    const int M = in_sizes[1] / (B * 3);
    const int NQ = (N > M ? N : M);
    const int NR = (N > M ? N : M);

    int S = 32;
    while (NR % (S * 8)) S >>= 1;  // need C = NR/S divisible by 8
    const int C = NR / S;          // C/8 groups <= 64 (u64 mask)

    unsigned long long* pp = (unsigned long long*)d_ws;  // [2][B][NQ] packed slots
    const int nslots = 2 * B * NQ;

    // init pp to ~0ULL via byte-pattern memset (0xFF) — graph-capturable
    // memset node, replaces the init kernel (one fewer dispatch + gap).
    hipMemsetAsync(pp, 0xFF, (size_t)nslots * 8, stream);

    dim3 grid((NQ + QPB - 1) / QPB, B * S, 2);
    size_t lds = (size_t)C * 4 * sizeof(float);   // float4 per ref point
    chamfer_main<<<grid, dim3(BLK, 1, 1), lds, stream>>>(
        xyz1, xyz2, pp, N, M, B, S, C);

    chamfer_final<<<dim3((nslots + 255) / 256, 1, 1), dim3(256, 1, 1), 0, stream>>>(
        xyz1, xyz2, pp, out, N, M, B);
}